// Round 10
// baseline (148.916 us; speedup 1.0000x reference)
//
#include <hip/hip_runtime.h>

// WeightedKappaLoss: kappa = 1 - (N * sum(W*conf)) / sum(W_ij * ht_i * hp_j)
// conf = 6x6 confusion histogram of (y_true, argmax(y_pred_row)).
// softmax is monotone -> argmax on raw logits. Counts exact; ratio in double
// -> absmax == 0 (verified R0/R2/R4-R8).
//
// R10 = R8 (144.0 us: sc1 nt streaming + coalesced LDS bounce + vmcnt(0)
// drain) with two independent, low-risk upgrades. R9's counted-vmcnt
// pipeline CORE-DUMPED: its register rotate reads in-flight asm-load dest
// registers (register-only v_movs escape asm memory-clobber ordering,
// rule #18) -- that approach is dead; R10 keeps R8's safe discipline
// (ALL loads drained by vmcnt(0) before ANY use).
//   1) Count: CHUNK 64 -> 128 pairs/wave-iter (6x dwordx4 + 2x dwordx2,
//      7 KB in flight, ONE vmcnt(0) stall per 128 pairs instead of per 64)
//      -- halves exposed-latency stalls in the uncached sc1-nt regime.
//   2) Final: partials stored TRANSPOSED gconf[bin][blk] so the single
//      final block reads each bin as contiguous uint4 (16 independent
//      loads/thread, deep MLP) instead of 64 scalar dwords at stride 144 B.
// Everything else unchanged: GRID=1024 x BLOCK=256 (16 waves/CU, R6/R8-
// proven; R7 showed 32 waves/CU is not better), per-wave LDS histograms,
// race-free partial store, two-kernel reduction (R2: fused last-block
// fan-in costs ~95 us -- never again).
// Fills (2 x 384 MB poison ~= 112 us @ ~84% peak) are harness-owned floor.

#define NC 6
#define NBINS 36
#define BLOCK 256
#define WPB (BLOCK / 64)            // 4 waves per block
#define GRID 1024                   // 4 blocks/CU, 16 waves/CU
#define CHUNK 128                   // pairs per wave-iteration (6 KB logits)
#define FIN_THREADS (NBINS * 16)    // 576 = 9 waves

typedef float f4 __attribute__((ext_vector_type(4)));

__device__ __forceinline__ f4 ld_stream_b128(const f4* p) {
    f4 r;
    asm volatile("global_load_dwordx4 %0, %1, off sc1 nt"
                 : "=v"(r) : "v"(p) : "memory");
    return r;
}
__device__ __forceinline__ unsigned long long ld_stream_b64(
    const unsigned long long* p) {
    unsigned long long r;
    asm volatile("global_load_dwordx2 %0, %1, off sc1 nt"
                 : "=v"(r) : "v"(p) : "memory");
    return r;
}

// argmax of one 6-logit row + histogram bump (strict > = first max = argmax)
__device__ __forceinline__ void bump(unsigned int* __restrict__ my, int t,
                                     float e0, float e1, float e2,
                                     float e3, float e4, float e5) {
    float m = e0; int p = 0;
    if (e1 > m) { m = e1; p = 1; }
    if (e2 > m) { m = e2; p = 2; }
    if (e3 > m) { m = e3; p = 3; }
    if (e4 > m) { m = e4; p = 4; }
    if (e5 > m) { m = e5; p = 5; }
    atomicAdd(&my[t * NC + p], 1u);
}

__global__ __launch_bounds__(BLOCK) void kappa_count(
    const f4* __restrict__ yp4, const unsigned long long* __restrict__ yt2,
    const float* __restrict__ yp, const int* __restrict__ yt,
    unsigned int* __restrict__ gconf, int npairs, int N) {
    __shared__ f4 stage[WPB][3 * CHUNK];          // 24 KB, wave-private rows
    __shared__ unsigned int sconf[WPB][NBINS];    // per-wave histograms
    const int tid = threadIdx.x;
    const int w = tid >> 6;
    const int L = tid & 63;
    if (tid < WPB * NBINS) ((unsigned int*)sconf)[tid] = 0u;
    __syncthreads();

    unsigned int* my = sconf[w];
    f4* st = stage[w];

    const int nchunks = npairs / CHUNK;           // 15625 for N=4e6 (exact)
    const int gwaves = GRID * WPB;                // 4096 waves in grid
    for (int c = blockIdx.x * WPB + w; c < nchunks; c += gwaves) {
        // Coalesced streaming loads: 6x 1KB logits + 2x 0.5KB labels; each
        // 64 B line touched by exactly one instruction (sc1 bypasses L2 ->
        // over-fetch would be fatal). 8 loads in flight per wave (7 KB).
        const f4 g0 = ld_stream_b128(&yp4[c * 3 * CHUNK + L]);
        const f4 g1 = ld_stream_b128(&yp4[c * 3 * CHUNK + 64 + L]);
        const f4 g2 = ld_stream_b128(&yp4[c * 3 * CHUNK + 128 + L]);
        const f4 g3 = ld_stream_b128(&yp4[c * 3 * CHUNK + 192 + L]);
        const f4 g4 = ld_stream_b128(&yp4[c * 3 * CHUNK + 256 + L]);
        const f4 g5 = ld_stream_b128(&yp4[c * 3 * CHUNK + 320 + L]);
        const unsigned long long t0v = ld_stream_b64(&yt2[c * CHUNK + L]);
        const unsigned long long t1v = ld_stream_b64(&yt2[c * CHUNK + 64 + L]);
        // Asm loads are not compiler-tracked: drain ALL before any use
        // (R8-proven safe discipline), pin schedule (rule #18).
        asm volatile("s_waitcnt vmcnt(0)" ::: "memory");
        __builtin_amdgcn_sched_barrier(0);
        st[L] = g0;
        st[64 + L] = g1;
        st[128 + L] = g2;
        st[192 + L] = g3;
        st[256 + L] = g4;
        st[320 + L] = g5;
        // ds_write -> ds_read ordering (cross-lane exchange): targeted
        // lgkmcnt(0) + sched_barrier (R4/R8-proven; memory clobber orders
        // the DS ops -- they are memory instructions).
        asm volatile("s_waitcnt lgkmcnt(0)" ::: "memory");
        __builtin_amdgcn_sched_barrier(0);
        // Pair A = c*CHUNK + L: rows in st[3L .. 3L+2]
        {
            const f4 a = st[3 * L];
            const f4 b = st[3 * L + 1];
            const f4 d = st[3 * L + 2];
            bump(my, (int)(t0v & 0xffffffffull), a.x, a.y, a.z, a.w, b.x, b.y);
            bump(my, (int)(t0v >> 32),           b.z, b.w, d.x, d.y, d.z, d.w);
        }
        // Pair B = c*CHUNK + 64 + L: rows in st[192 + 3L .. 192 + 3L+2]
        {
            const f4 a = st[192 + 3 * L];
            const f4 b = st[192 + 3 * L + 1];
            const f4 d = st[192 + 3 * L + 2];
            bump(my, (int)(t1v & 0xffffffffull), a.x, a.y, a.z, a.w, b.x, b.y);
            bump(my, (int)(t1v >> 32),           b.z, b.w, d.x, d.y, d.z, d.w);
        }
        // Inter-iteration LDS WAR (reads here vs writes next iter) is
        // compiler-ordered by the next iter's asm memory clobbers and
        // HW-ordered by the per-wave in-order DS pipe (R8-verified).
    }

    // leftover pairs (npairs % CHUNK; zero for N=4e6) — plain direct loads
    const int rem0 = nchunks * CHUNK;
    if (blockIdx.x == 0 && tid < npairs - rem0) {
        const int i = rem0 + tid;
        const f4 a = yp4[3 * i];
        const f4 b = yp4[3 * i + 1];
        const f4 d = yp4[3 * i + 2];
        const unsigned long long tt = yt2[i];
        bump(my, (int)(tt & 0xffffffffull), a.x, a.y, a.z, a.w, b.x, b.y);
        bump(my, (int)(tt >> 32),           b.z, b.w, d.x, d.y, d.z, d.w);
    }

    // odd-N tail row (N=4e6 is even; kept for generality)
    if ((N & 1) && blockIdx.x == 0 && tid == 0) {
        const int r = N - 1;
        float m = yp[r * NC]; int p = 0;
        #pragma unroll
        for (int j = 1; j < NC; ++j) {
            const float v = yp[r * NC + j];
            if (v > m) { m = v; p = j; }
        }
        atomicAdd(&my[yt[r] * NC + p], 1u);
    }

    __syncthreads();
    // Race-free per-block writedown, TRANSPOSED: gconf[bin][blk] so the
    // final kernel reads each bin as a contiguous 4 KB run. 36 scattered
    // dword stores per block (trivial volume). No global atomics, no fences.
    if (tid < NBINS) {
        unsigned int s = 0;
        #pragma unroll
        for (int k = 0; k < WPB; ++k) s += sconf[k][tid];
        gconf[tid * GRID + blockIdx.x] = s;
    }
}

__global__ void kappa_final_kernel(const unsigned int* __restrict__ gconf,
                                   float* __restrict__ out, long long N) {
    // 576 threads; bin = tid/16 reads its 1024 partials as 16 seg-slices of
    // contiguous uint4 (16 independent loads/thread -> deep MLP, coalesced
    // 64 B segments). 144 KB total, ~2-3 us.
    __shared__ unsigned int part[NBINS][16];
    __shared__ unsigned int conf_s[NBINS];
    const int tid = threadIdx.x;
    {
        const int bin = tid >> 4;          // 0..35
        const int seg = tid & 15;          // 0..15
        const uint4* g4 = (const uint4*)gconf;   // 256 uint4 per bin row
        unsigned int s = 0;
        #pragma unroll
        for (int j = 0; j < 16; ++j) {
            const uint4 v = g4[bin * 256 + seg * 16 + j];
            s += v.x + v.y + v.z + v.w;
        }
        part[bin][seg] = s;
    }
    __syncthreads();
    if (tid < NBINS) {
        unsigned int tot = 0;
        #pragma unroll
        for (int s2 = 0; s2 < 16; ++s2) tot += part[tid][s2];
        conf_s[tid] = tot;   // per-bin total <= N=4e6, exact in u32
    }
    __syncthreads();
    if (tid == 0) {
        long long conf[NBINS], ht[NC], hp[NC];
        #pragma unroll
        for (int i = 0; i < NC; ++i) { ht[i] = 0; hp[i] = 0; }
        #pragma unroll
        for (int k = 0; k < NBINS; ++k) conf[k] = (long long)conf_s[k];

        long long num = 0;
        #pragma unroll
        for (int i = 0; i < NC; ++i)
            #pragma unroll
            for (int j = 0; j < NC; ++j) {
                const long long w = (long long)(i - j) * (i - j);
                num += w * conf[i * NC + j];
                ht[i] += conf[i * NC + j];
                hp[j] += conf[i * NC + j];
            }
        long long den = 0;
        #pragma unroll
        for (int i = 0; i < NC; ++i)
            #pragma unroll
            for (int j = 0; j < NC; ++j)
                den += (long long)(i - j) * (i - j) * ht[i] * hp[j];

        out[0] = (float)(1.0 - ((double)num * (double)N) / (double)den);
    }
}

extern "C" void kernel_launch(void* const* d_in, const int* in_sizes, int n_in,
                              void* d_out, int out_size, void* d_ws, size_t ws_size,
                              hipStream_t stream) {
    const float* yp = (const float*)d_in[0];
    const int* yt = (const int*)d_in[1];   // int32 on device (verified: absmax=0)
    const int N = in_sizes[1];
    unsigned int* gconf = (unsigned int*)d_ws;  // NBINS*GRID uints = 144 KB

    const int npairs = N / 2;
    kappa_count<<<GRID, BLOCK, 0, stream>>>(
        (const f4*)yp, (const unsigned long long*)yt, yp, yt, gconf, npairs, N);
    kappa_final_kernel<<<1, FIN_THREADS, 0, stream>>>(gconf, (float*)d_out,
                                                      (long long)N);
}

// Round 11
// 146.238 us; speedup vs baseline: 1.0183x; 1.0183x over previous
//
#include <hip/hip_runtime.h>

// WeightedKappaLoss: kappa = 1 - (N * sum(W*conf)) / sum(W_ij * ht_i * hp_j)
// conf = 6x6 confusion histogram of (y_true, argmax(y_pred_row)).
// softmax is monotone -> argmax on raw logits. Counts exact; ratio in double
// -> absmax == 0 (verified R0/R2/R4-R8/R10).
//
// R11 = R8's count loop VERBATIM (144.0 us best: sc1 nt streaming loads,
// CHUNK=64, coalesced LDS bounce, vmcnt(0) drain discipline) + ONLY the
// transposed-partials final stage from R10. Single-knob A/B vs R8.
// R10 post-mortem: CHUNK=128 regressed (+5 us): 8 in-flight loads x 16
// waves/CU = 112 KB outstanding per CU exceeds the vmem queue depth in the
// uncached sc1-nt regime -> issue-side throttling. CHUNK=64 restored.
// R8 decomposition: 144 ~= 114 fills (harness-owned) + ~19 count (112 MB
// @ 5.9 TB/s, near 17.8 us streaming floor) + ~8 final + ~3 gaps. The
// final kernel's 36864 stride-144B scalar loads (mostly remote-XCD L2,
// 500-900 cyc) are the last lever: transposed gconf[bin][blk] lets the
// final block read each bin as contiguous uint4 (16 independent 64 B
// loads/thread, deep MLP) -> ~2-3 us.
// Count-side cost of transpose: 36 scattered dword stores per block
// (36 K total, write-combined) -- negligible.
// Structure: GRID=1024 x BLOCK=256 (16 waves/CU; R7 showed 32 is not
// better), per-wave LDS histograms, race-free partial store, two-kernel
// reduction (R2: fused last-block fan-in costs ~95 us -- never again).

#define NC 6
#define NBINS 36
#define BLOCK 256
#define WPB (BLOCK / 64)            // 4 waves per block
#define GRID 1024                   // 4 blocks/CU, 16 waves/CU
#define CHUNK 64                    // pairs per wave-iteration (3 KB logits)
#define FIN_THREADS (NBINS * 16)    // 576 = 9 waves

typedef float f4 __attribute__((ext_vector_type(4)));

__device__ __forceinline__ f4 ld_stream_b128(const f4* p) {
    f4 r;
    asm volatile("global_load_dwordx4 %0, %1, off sc1 nt"
                 : "=v"(r) : "v"(p) : "memory");
    return r;
}
__device__ __forceinline__ unsigned long long ld_stream_b64(
    const unsigned long long* p) {
    unsigned long long r;
    asm volatile("global_load_dwordx2 %0, %1, off sc1 nt"
                 : "=v"(r) : "v"(p) : "memory");
    return r;
}

__global__ __launch_bounds__(BLOCK) void kappa_count(
    const f4* __restrict__ yp4, const unsigned long long* __restrict__ yt2,
    const float* __restrict__ yp, const int* __restrict__ yt,
    unsigned int* __restrict__ gconf, int npairs, int N) {
    __shared__ f4 stage[WPB][3 * CHUNK];          // 12 KB, wave-private rows
    __shared__ unsigned int sconf[WPB][NBINS];    // per-wave histograms
    const int tid = threadIdx.x;
    const int w = tid >> 6;
    const int L = tid & 63;
    if (tid < WPB * NBINS) ((unsigned int*)sconf)[tid] = 0u;
    __syncthreads();

    unsigned int* my = sconf[w];
    f4* st = stage[w];

    const int nchunks = npairs / CHUNK;
    const int gwaves = GRID * WPB;                // 4096 waves in grid
    for (int c = blockIdx.x * WPB + w; c < nchunks; c += gwaves) {
        // Coalesced streaming loads: each 64 B line touched by exactly one
        // instruction (sc1 bypasses L2 -> over-fetch would be fatal here).
        const f4 g0 = ld_stream_b128(&yp4[c * 3 * CHUNK + L]);
        const f4 g1 = ld_stream_b128(&yp4[c * 3 * CHUNK + 64 + L]);
        const f4 g2 = ld_stream_b128(&yp4[c * 3 * CHUNK + 128 + L]);
        const unsigned long long tt = ld_stream_b64(&yt2[c * CHUNK + L]);
        // Asm loads are not compiler-tracked: drain vmcnt before LDS writes,
        // and pin the schedule (rule #18).
        asm volatile("s_waitcnt vmcnt(0)" ::: "memory");
        __builtin_amdgcn_sched_barrier(0);
        st[L] = g0;
        st[64 + L] = g1;
        st[128 + L] = g2;
        // Cross-lane exchange through LDS: fence REQUIRED (R3 post-mortem);
        // orders ds_write before ds_read at IR level + waits lgkmcnt(0).
        __threadfence_block();
        const f4 a = st[3 * L];
        const f4 b = st[3 * L + 1];
        const f4 d = st[3 * L + 2];
        const int t0 = (int)(tt & 0xffffffffull);
        const int t1 = (int)(tt >> 32);

        // row 0: a0 a1 a2 a3 b0 b1 (strict > keeps first max = jnp.argmax)
        float m = a.x; int p = 0;
        if (a.y > m) { m = a.y; p = 1; }
        if (a.z > m) { m = a.z; p = 2; }
        if (a.w > m) { m = a.w; p = 3; }
        if (b.x > m) { m = b.x; p = 4; }
        if (b.y > m) { m = b.y; p = 5; }
        atomicAdd(&my[t0 * NC + p], 1u);

        // row 1: b2 b3 d0 d1 d2 d3
        m = b.z; p = 0;
        if (b.w > m) { m = b.w; p = 1; }
        if (d.x > m) { m = d.x; p = 2; }
        if (d.y > m) { m = d.y; p = 3; }
        if (d.z > m) { m = d.z; p = 4; }
        if (d.w > m) { m = d.w; p = 5; }
        atomicAdd(&my[t1 * NC + p], 1u);
    }

    // leftover pairs (npairs % 64; zero for N=4e6) — plain direct loads
    const int rem0 = nchunks * CHUNK;
    if (blockIdx.x == 0 && tid < npairs - rem0) {
        const int i = rem0 + tid;
        const f4 a = yp4[3 * i];
        const f4 b = yp4[3 * i + 1];
        const f4 d = yp4[3 * i + 2];
        const unsigned long long tt = yt2[i];
        const int t0 = (int)(tt & 0xffffffffull);
        const int t1 = (int)(tt >> 32);
        float m = a.x; int p = 0;
        if (a.y > m) { m = a.y; p = 1; }
        if (a.z > m) { m = a.z; p = 2; }
        if (a.w > m) { m = a.w; p = 3; }
        if (b.x > m) { m = b.x; p = 4; }
        if (b.y > m) { m = b.y; p = 5; }
        atomicAdd(&my[t0 * NC + p], 1u);
        m = b.z; p = 0;
        if (b.w > m) { m = b.w; p = 1; }
        if (d.x > m) { m = d.x; p = 2; }
        if (d.y > m) { m = d.y; p = 3; }
        if (d.z > m) { m = d.z; p = 4; }
        if (d.w > m) { m = d.w; p = 5; }
        atomicAdd(&my[t1 * NC + p], 1u);
    }

    // odd-N tail row (N=4e6 is even; kept for generality)
    if ((N & 1) && blockIdx.x == 0 && tid == 0) {
        const int r = N - 1;
        float m = yp[r * NC]; int p = 0;
        #pragma unroll
        for (int j = 1; j < NC; ++j) {
            const float v = yp[r * NC + j];
            if (v > m) { m = v; p = j; }
        }
        atomicAdd(&my[yt[r] * NC + p], 1u);
    }

    __syncthreads();
    // Race-free per-block writedown, TRANSPOSED: gconf[bin][blk] so the
    // final kernel reads each bin as a contiguous 4 KB run. 36 scattered
    // dword stores per block (trivial volume). No global atomics, no fences.
    if (tid < NBINS) {
        unsigned int s = 0;
        #pragma unroll
        for (int k = 0; k < WPB; ++k) s += sconf[k][tid];
        gconf[tid * GRID + blockIdx.x] = s;
    }
}

__global__ void kappa_final_kernel(const unsigned int* __restrict__ gconf,
                                   float* __restrict__ out, long long N) {
    // 576 threads; bin = tid/16 reads its 1024 partials as 16 seg-slices of
    // contiguous uint4 (16 independent loads/thread -> deep MLP, coalesced
    // 64 B segments). 144 KB total, ~2-3 us.
    __shared__ unsigned int part[NBINS][16];
    __shared__ unsigned int conf_s[NBINS];
    const int tid = threadIdx.x;
    {
        const int bin = tid >> 4;          // 0..35
        const int seg = tid & 15;          // 0..15
        const uint4* g4 = (const uint4*)gconf;   // 256 uint4 per bin row
        unsigned int s = 0;
        #pragma unroll
        for (int j = 0; j < 16; ++j) {
            const uint4 v = g4[bin * 256 + seg * 16 + j];
            s += v.x + v.y + v.z + v.w;
        }
        part[bin][seg] = s;
    }
    __syncthreads();
    if (tid < NBINS) {
        unsigned int tot = 0;
        #pragma unroll
        for (int s2 = 0; s2 < 16; ++s2) tot += part[tid][s2];
        conf_s[tid] = tot;   // per-bin total <= N=4e6, exact in u32
    }
    __syncthreads();
    if (tid == 0) {
        long long conf[NBINS], ht[NC], hp[NC];
        #pragma unroll
        for (int i = 0; i < NC; ++i) { ht[i] = 0; hp[i] = 0; }
        #pragma unroll
        for (int k = 0; k < NBINS; ++k) conf[k] = (long long)conf_s[k];

        long long num = 0;
        #pragma unroll
        for (int i = 0; i < NC; ++i)
            #pragma unroll
            for (int j = 0; j < NC; ++j) {
                const long long w = (long long)(i - j) * (i - j);
                num += w * conf[i * NC + j];
                ht[i] += conf[i * NC + j];
                hp[j] += conf[i * NC + j];
            }
        long long den = 0;
        #pragma unroll
        for (int i = 0; i < NC; ++i)
            #pragma unroll
            for (int j = 0; j < NC; ++j)
                den += (long long)(i - j) * (i - j) * ht[i] * hp[j];

        out[0] = (float)(1.0 - ((double)num * (double)N) / (double)den);
    }
}

extern "C" void kernel_launch(void* const* d_in, const int* in_sizes, int n_in,
                              void* d_out, int out_size, void* d_ws, size_t ws_size,
                              hipStream_t stream) {
    const float* yp = (const float*)d_in[0];
    const int* yt = (const int*)d_in[1];   // int32 on device (verified: absmax=0)
    const int N = in_sizes[1];
    unsigned int* gconf = (unsigned int*)d_ws;  // NBINS*GRID uints = 144 KB

    const int npairs = N / 2;
    kappa_count<<<GRID, BLOCK, 0, stream>>>(
        (const f4*)yp, (const unsigned long long*)yt, yp, yt, gconf, npairs, N);
    kappa_final_kernel<<<1, FIN_THREADS, 0, stream>>>(gconf, (float*)d_out,
                                                      (long long)N);
}

// Round 13
// 145.995 us; speedup vs baseline: 1.0200x; 1.0017x over previous
//
#include <hip/hip_runtime.h>

// WeightedKappaLoss: kappa = 1 - (N * sum(W*conf)) / sum(W_ij * ht_i * hp_j)
// conf = 6x6 confusion histogram of (y_true, argmax(y_pred_row)).
// softmax is monotone -> argmax on raw logits. Counts exact; ratio in double
// -> absmax == 0 (verified R0/R2/R4-R8/R10/R11).
//
// R13 = R12 = R8 BYTE-FOR-BYTE (session's verified best: 144.0 us).
// R12 never ran: GPUAcquisitionTimeout (infra). Resubmitting unchanged for
// the reproducibility check before declaring roofline.
// Full ledger:
//   R0  153.3  baseline (direct stride-48 loads, two-kernel reduction)
//   R2  244.4  fused last-block fan-in: 2048 same-address device atomics +
//              per-block threadfence ~= +95 us. NEVER fuse on this chip.
//   R4  155.6  LDS bounce + per-chunk __threadfence_block: neutral
//   R5  157.5  4-deep register MLP: neutral/negative
//   R6  148.8  __builtin_nontemporal_load: WIN (+4.5) -- L3 allocation
//              fights the harness's fill-dirtied 256 MB L3
//   R7  152.1  32 waves/CU: negative (not parallelism-bound)
//   R8  144.0  asm "sc1 nt" streaming loads + coalesced LDS bounce: WIN
//              (+4.8) -- full cache-bypass, each 64B line fetched once
//   R9  crash  counted-vmcnt pipeline: register rotate reads in-flight asm
//              dest regs (rule #18) -- unsalvageable at HIP source level
//   R10 148.9  CHUNK=128: negative (vmem queue depth exceeded)
//   R11 146.2  transposed partials + uint4 final: neutral -- residual is
//              launch overhead, not final-kernel read pattern
// Decomposition: ~114 us harness poison fills (83-85% peak, untouchable)
// + ~19-20 us count (112 MB @ ~5.9 TB/s, ~10% off the 17.8 us streaming
// floor) + ~8-10 us final/launch/gaps. This is the practical roofline.

#define NC 6
#define NBINS 36
#define BLOCK 256
#define WPB (BLOCK / 64)            // 4 waves per block
#define GRID 1024                   // 4 blocks/CU, 16 waves/CU
#define CHUNK 64                    // pairs per wave-iteration (3 KB logits)
#define SEGS 16
#define FIN_THREADS (NBINS * SEGS)  // 576 = 9 waves

typedef float f4 __attribute__((ext_vector_type(4)));

__device__ __forceinline__ f4 ld_stream_b128(const f4* p) {
    f4 r;
    asm volatile("global_load_dwordx4 %0, %1, off sc1 nt"
                 : "=v"(r) : "v"(p) : "memory");
    return r;
}
__device__ __forceinline__ unsigned long long ld_stream_b64(
    const unsigned long long* p) {
    unsigned long long r;
    asm volatile("global_load_dwordx2 %0, %1, off sc1 nt"
                 : "=v"(r) : "v"(p) : "memory");
    return r;
}

__global__ __launch_bounds__(BLOCK) void kappa_count(
    const f4* __restrict__ yp4, const unsigned long long* __restrict__ yt2,
    const float* __restrict__ yp, const int* __restrict__ yt,
    unsigned int* __restrict__ gconf, int npairs, int N) {
    __shared__ f4 stage[WPB][3 * CHUNK];          // 12 KB, wave-private rows
    __shared__ unsigned int sconf[WPB][NBINS];    // per-wave histograms
    const int tid = threadIdx.x;
    const int w = tid >> 6;
    const int L = tid & 63;
    if (tid < WPB * NBINS) ((unsigned int*)sconf)[tid] = 0u;
    __syncthreads();

    unsigned int* my = sconf[w];
    f4* st = stage[w];

    const int nchunks = npairs / CHUNK;
    const int gwaves = GRID * WPB;                // 4096 waves in grid
    for (int c = blockIdx.x * WPB + w; c < nchunks; c += gwaves) {
        // Coalesced streaming loads: each 64 B line touched by exactly one
        // instruction (sc1 bypasses L2 -> over-fetch would be fatal here).
        const f4 g0 = ld_stream_b128(&yp4[c * 3 * CHUNK + L]);
        const f4 g1 = ld_stream_b128(&yp4[c * 3 * CHUNK + 64 + L]);
        const f4 g2 = ld_stream_b128(&yp4[c * 3 * CHUNK + 128 + L]);
        const unsigned long long tt = ld_stream_b64(&yt2[c * CHUNK + L]);
        // Asm loads are not compiler-tracked: drain vmcnt before LDS writes,
        // and pin the schedule (rule #18).
        asm volatile("s_waitcnt vmcnt(0)" ::: "memory");
        __builtin_amdgcn_sched_barrier(0);
        st[L] = g0;
        st[64 + L] = g1;
        st[128 + L] = g2;
        // Cross-lane exchange through LDS: fence REQUIRED (R3 post-mortem);
        // orders ds_write before ds_read at IR level + waits lgkmcnt(0).
        __threadfence_block();
        const f4 a = st[3 * L];
        const f4 b = st[3 * L + 1];
        const f4 d = st[3 * L + 2];
        const int t0 = (int)(tt & 0xffffffffull);
        const int t1 = (int)(tt >> 32);

        // row 0: a0 a1 a2 a3 b0 b1 (strict > keeps first max = jnp.argmax)
        float m = a.x; int p = 0;
        if (a.y > m) { m = a.y; p = 1; }
        if (a.z > m) { m = a.z; p = 2; }
        if (a.w > m) { m = a.w; p = 3; }
        if (b.x > m) { m = b.x; p = 4; }
        if (b.y > m) { m = b.y; p = 5; }
        atomicAdd(&my[t0 * NC + p], 1u);

        // row 1: b2 b3 d0 d1 d2 d3
        m = b.z; p = 0;
        if (b.w > m) { m = b.w; p = 1; }
        if (d.x > m) { m = d.x; p = 2; }
        if (d.y > m) { m = d.y; p = 3; }
        if (d.z > m) { m = d.z; p = 4; }
        if (d.w > m) { m = d.w; p = 5; }
        atomicAdd(&my[t1 * NC + p], 1u);
    }

    // leftover pairs (npairs % 64; zero for N=4e6) — plain direct loads
    const int rem0 = nchunks * CHUNK;
    if (blockIdx.x == 0 && tid < npairs - rem0) {
        const int i = rem0 + tid;
        const f4 a = yp4[3 * i];
        const f4 b = yp4[3 * i + 1];
        const f4 d = yp4[3 * i + 2];
        const unsigned long long tt = yt2[i];
        const int t0 = (int)(tt & 0xffffffffull);
        const int t1 = (int)(tt >> 32);
        float m = a.x; int p = 0;
        if (a.y > m) { m = a.y; p = 1; }
        if (a.z > m) { m = a.z; p = 2; }
        if (a.w > m) { m = a.w; p = 3; }
        if (b.x > m) { m = b.x; p = 4; }
        if (b.y > m) { m = b.y; p = 5; }
        atomicAdd(&my[t0 * NC + p], 1u);
        m = b.z; p = 0;
        if (b.w > m) { m = b.w; p = 1; }
        if (d.x > m) { m = d.x; p = 2; }
        if (d.y > m) { m = d.y; p = 3; }
        if (d.z > m) { m = d.z; p = 4; }
        if (d.w > m) { m = d.w; p = 5; }
        atomicAdd(&my[t1 * NC + p], 1u);
    }

    // odd-N tail row (N=4e6 is even; kept for generality)
    if ((N & 1) && blockIdx.x == 0 && tid == 0) {
        const int r = N - 1;
        float m = yp[r * NC]; int p = 0;
        #pragma unroll
        for (int j = 1; j < NC; ++j) {
            const float v = yp[r * NC + j];
            if (v > m) { m = v; p = j; }
        }
        atomicAdd(&my[yt[r] * NC + p], 1u);
    }

    __syncthreads();
    // Race-free per-block writedown: merge 4 wave histograms, one coalesced
    // 144 B store per block. No global atomics, no fences, no prior memset.
    if (tid < NBINS) {
        unsigned int s = 0;
        #pragma unroll
        for (int k = 0; k < WPB; ++k) s += sconf[k][tid];
        gconf[blockIdx.x * NBINS + tid] = s;
    }
}

__global__ void kappa_final_kernel(const unsigned int* __restrict__ gconf,
                                   float* __restrict__ out, long long N) {
    // 576 threads, each sums 64 of the 1024 partials for one bin (9 waves,
    // independent unrolled loads -> latency hidden). R11 measured the
    // transposed/uint4 variant equal-or-worse: this stage is launch-bound.
    __shared__ unsigned int part[SEGS][NBINS];
    __shared__ unsigned int conf_s[NBINS];
    const int tid = threadIdx.x;
    if (tid < FIN_THREADS) {
        const int bin = tid % NBINS;
        const int seg = tid / NBINS;
        unsigned int s = 0;
        const int b0 = seg * (GRID / SEGS);
        #pragma unroll 8
        for (int b = b0; b < b0 + GRID / SEGS; ++b) s += gconf[b * NBINS + bin];
        part[seg][bin] = s;
    }
    __syncthreads();
    if (tid < NBINS) {
        unsigned int tot = 0;
        #pragma unroll
        for (int s2 = 0; s2 < SEGS; ++s2) tot += part[s2][tid];
        conf_s[tid] = tot;   // per-bin total <= N=4e6, exact in u32
    }
    __syncthreads();
    if (tid == 0) {
        long long conf[NBINS], ht[NC], hp[NC];
        #pragma unroll
        for (int i = 0; i < NC; ++i) { ht[i] = 0; hp[i] = 0; }
        #pragma unroll
        for (int k = 0; k < NBINS; ++k) conf[k] = (long long)conf_s[k];

        long long num = 0;
        #pragma unroll
        for (int i = 0; i < NC; ++i)
            #pragma unroll
            for (int j = 0; j < NC; ++j) {
                const long long w = (long long)(i - j) * (i - j);
                num += w * conf[i * NC + j];
                ht[i] += conf[i * NC + j];
                hp[j] += conf[i * NC + j];
            }
        long long den = 0;
        #pragma unroll
        for (int i = 0; i < NC; ++i)
            #pragma unroll
            for (int j = 0; j < NC; ++j)
                den += (long long)(i - j) * (i - j) * ht[i] * hp[j];

        out[0] = (float)(1.0 - ((double)num * (double)N) / (double)den);
    }
}

extern "C" void kernel_launch(void* const* d_in, const int* in_sizes, int n_in,
                              void* d_out, int out_size, void* d_ws, size_t ws_size,
                              hipStream_t stream) {
    const float* yp = (const float*)d_in[0];
    const int* yt = (const int*)d_in[1];   // int32 on device (verified: absmax=0)
    const int N = in_sizes[1];
    unsigned int* gconf = (unsigned int*)d_ws;  // GRID*NBINS uints = 144 KB

    const int npairs = N / 2;
    kappa_count<<<GRID, BLOCK, 0, stream>>>(
        (const f4*)yp, (const unsigned long long*)yt, yp, yt, gconf, npairs, N);
    kappa_final_kernel<<<1, FIN_THREADS, 0, stream>>>(gconf, (float*)d_out,
                                                      (long long)N);
}